// Round 18
// baseline (216.112 us; speedup 1.0000x reference)
//
#include <hip/hip_runtime.h>
#include <hip/hip_fp16.h>
#include <stdint.h>
#include <stddef.h>

// B=4, S=2048, E=1024, H=16, D=64, M=32
// fp16 MFMA pipeline with fp32 accumulation everywhere.

typedef _Float16 half8 __attribute__((ext_vector_type(8)));
typedef _Float16 half2v __attribute__((ext_vector_type(2)));
typedef float f32x4 __attribute__((ext_vector_type(4)));
typedef float f32x16 __attribute__((ext_vector_type(16)));
typedef uint32_t u32x4 __attribute__((ext_vector_type(4)));

#define MFMA16(a, b, c) __builtin_amdgcn_mfma_f32_16x16x32_f16(a, b, c, 0, 0, 0)
#define MFMA32(a, b, c) __builtin_amdgcn_mfma_f32_32x32x16_f16(a, b, c, 0, 0, 0)

__device__ static inline void gload_lds16(const void* g, void* l) {
  __builtin_amdgcn_global_load_lds(
      (const __attribute__((address_space(1))) void*)g,
      (__attribute__((address_space(3))) void*)l, 16, 0, 0);
}

// single-instruction packed f32->f16 (RTZ) convert: v_cvt_pkrtz_f16_f32
__device__ static inline uint32_t pkrtz(float a, float b) {
  return __builtin_bit_cast(uint32_t, __builtin_amdgcn_cvt_pkrtz(a, b));
}

// ---- fused f32->f16 conversion for x / in_w / out_w + rel_bias mean --------
__global__ void cvt_all(const float* __restrict__ x, const float* __restrict__ w,
                        const float* __restrict__ ow, const float* __restrict__ rb,
                        __half* __restrict__ xh, __half* __restrict__ wh,
                        __half* __restrict__ owh, float* __restrict__ mbg,
                        int nx, int nw, int no) {
  if (blockIdx.x == 0 && threadIdx.x < 65) {
    float s = 0.f;
    #pragma unroll
    for (int hh = 0; hh < 16; ++hh) s += rb[threadIdx.x * 16 + hh];
    mbg[threadIdx.x] = s * (1.44269504f / 16.f);  // mean * log2(e)
  }
  const int total = nx + nw + no;
  int i = blockIdx.x * blockDim.x + threadIdx.x;
  const int stride = gridDim.x * blockDim.x;
  for (; i < total; i += stride) {
    const float* src; __half* dst; int j;
    if (i < nx)            { src = x;  dst = xh;  j = i; }
    else if (i < nx + nw)  { src = w;  dst = wh;  j = i - nx; }
    else                   { src = ow; dst = owh; j = i - nx - nw; }
    const float4* p = (const float4*)src + (size_t)j * 2;
    float4 a = p[0], b = p[1];
    half8 hv;
    hv[0] = (_Float16)a.x; hv[1] = (_Float16)a.y; hv[2] = (_Float16)a.z; hv[3] = (_Float16)a.w;
    hv[4] = (_Float16)b.x; hv[5] = (_Float16)b.y; hv[6] = (_Float16)b.z; hv[7] = (_Float16)b.w;
    *(half8*)(dst + (size_t)j * 8) = hv;
  }
}

// ---------------- m97-style GEMM, 3-buffer pipelined staging ----------------
// One barrier per K-step; stage kt+2 right after the barrier; the vmcnt(0)
// drain at barrier kt waits on loads issued a full K-step earlier (~free).
// LDS 48 KB -> 3 blocks/CU. XCD-swizzled grid (nwg % 8 == 0).
// Used for gemm2 (N=1024: a 256^2 grid would be only 128 blocks = half-idle).
template <bool OUT_HALF>
__global__ __launch_bounds__(256)
void gemm_bt(const __half* __restrict__ A, const __half* __restrict__ Bm,
             const float* __restrict__ bias, void* __restrict__ Cout,
             int Ndim, int K) {
  __shared__ __align__(16) __half As[3][128 * 32];
  __shared__ __align__(16) __half Bs[3][128 * 32];
  const int tid = threadIdx.x;
  const int lane = tid & 63;
  const int wave = tid >> 6;
  const int wr = wave >> 1, wc = wave & 1;
  const int flat = blockIdx.y * gridDim.x + blockIdx.x;
  const int cpx = (gridDim.x * gridDim.y) >> 3;
  const int nid = (flat & 7) * cpx + (flat >> 3);
  const int bn = nid % gridDim.x;
  const int bm = nid / gridDim.x;
  const int l15 = lane & 15;
  const int kseg = lane >> 4;

  const int off0 = tid * 16;
  const int mloc0 = off0 >> 6, kb0 = off0 & 63;
  const int off1 = 4096 + tid * 16;
  const int mloc1 = off1 >> 6, kb1 = off1 & 63;
  const __half* a0 = A + (size_t)(bm * 128 + mloc0) * K + (kb0 >> 1);
  const __half* a1 = A + (size_t)(bm * 128 + mloc1) * K + (kb1 >> 1);
  const __half* b0 = Bm + (size_t)(bn * 128 + mloc0) * K + (kb0 >> 1);
  const __half* b1 = Bm + (size_t)(bn * 128 + mloc1) * K + (kb1 >> 1);

  auto stage = [&](int kt, int buf) {
    char* ad = (char*)As[buf] + wave * 1024;
    char* bd = (char*)Bs[buf] + wave * 1024;
    gload_lds16(a0 + kt * 32, ad);
    gload_lds16(a1 + kt * 32, ad + 4096);
    gload_lds16(b0 + kt * 32, bd);
    gload_lds16(b1 + kt * 32, bd + 4096);
  };

  f32x4 acc[4][4];
  #pragma unroll
  for (int i = 0; i < 4; ++i)
    #pragma unroll
    for (int j = 0; j < 4; ++j) {
      acc[i][j][0] = 0.f; acc[i][j][1] = 0.f; acc[i][j][2] = 0.f; acc[i][j][3] = 0.f;
    }

  const int nk = K >> 5;
  stage(0, 0);
  stage(1, 1);

  int buf = 0;
  for (int kt = 0; kt < nk; ++kt) {
    __syncthreads();
    if (kt + 2 < nk) {
      int nb = buf + 2; if (nb >= 3) nb -= 3;
      stage(kt + 2, nb);
    }
    const __half* as = As[buf];
    const __half* bs = Bs[buf];
    half8 af[4], bf[4];
    #pragma unroll
    for (int i = 0; i < 4; ++i) {
      af[i] = *(const half8*)&as[(wr * 64 + i * 16 + l15) * 32 + kseg * 8];
      bf[i] = *(const half8*)&bs[(wc * 64 + i * 16 + l15) * 32 + kseg * 8];
    }
    #pragma unroll
    for (int i = 0; i < 4; ++i)
      #pragma unroll
      for (int j = 0; j < 4; ++j)
        acc[i][j] = MFMA16(af[i], bf[j], acc[i][j]);
    if (++buf == 3) buf = 0;
  }

  const int crow0 = bm * 128 + wr * 64;
  const int ccol0 = bn * 128 + wc * 64;
  #pragma unroll
  for (int j = 0; j < 4; ++j) {
    const int c = ccol0 + j * 16 + l15;
    const float bv = bias[c];
    #pragma unroll
    for (int i = 0; i < 4; ++i) {
      #pragma unroll
      for (int r = 0; r < 4; ++r) {
        const int row = crow0 + i * 16 + kseg * 4 + r;
        const float v = acc[i][j][r] + bv;
        if (OUT_HALF)
          ((__half*)Cout)[(size_t)row * Ndim + c] = __float2half_rn(v);
        else
          ((float*)Cout)[(size_t)row * Ndim + c] = v;
      }
    }
  }
}

// ---------------- 256^2-tile GEMM for gemm1 (round-18) ----------------------
// BM=BN=256, BK=64, 512 threads (8 waves, 2M x 4N, per-wave 128x64 output).
// LDS-read amortization: 24 b128 reads per 64 MFMA/wave-kt (vs 8/16 at 128^2,
// -25%); staging bytes/flop halved. 2 LDS buffers (128 KB), one barrier per
// K-step; drain covers a full K-step (round-15 pattern). 128B rows => XOR
// swizzle byte ^= ((row&7)<<4) with pre-swizzled global_load_lds source
// (attn-proven pattern). ~210 VGPR -> 2 waves/SIMD, 1 block/CU.
__global__ __launch_bounds__(512)
void gemm256(const __half* __restrict__ A, const __half* __restrict__ Bm,
             const float* __restrict__ bias, __half* __restrict__ Cout,
             int Ndim, int K) {
  __shared__ __align__(16) __half As[2][256 * 64];
  __shared__ __align__(16) __half Bs[2][256 * 64];   // total 128 KB

  const int tid = threadIdx.x;
  const int lane = tid & 63;
  const int w = tid >> 6;
  const int wr = w >> 2, wc = w & 3;       // 2M x 4N wave grid
  const int l15 = lane & 15;
  const int kseg = lane >> 4;              // 0..3
  const int swzr = (l15 & 7) << 4;         // read-side XOR

  const int flat = blockIdx.y * gridDim.x + blockIdx.x;
  const int cpx = (gridDim.x * gridDim.y) >> 3;
  const int nid = (flat & 7) * cpx + (flat >> 3);
  const int bn = nid % gridDim.x;
  const int bm = nid / gridDim.x;

  // staging: 4 chunks each for A,B; chunk c covers rows c*64 + (tid>>3),
  // 16B at col-byte (tid&7)*16, source pre-swizzled by ((row&7)<<4).
  const int r0 = tid >> 3;                                   // 0..63
  const int swcolh = ((((tid & 7) * 16) ^ ((r0 & 7) << 4)) >> 1); // halves
  const __half* pa0 = A + (size_t)(bm * 256 + 0 * 64 + r0) * K + swcolh;
  const __half* pa1 = A + (size_t)(bm * 256 + 1 * 64 + r0) * K + swcolh;
  const __half* pa2 = A + (size_t)(bm * 256 + 2 * 64 + r0) * K + swcolh;
  const __half* pa3 = A + (size_t)(bm * 256 + 3 * 64 + r0) * K + swcolh;
  const __half* pb0 = Bm + (size_t)(bn * 256 + 0 * 64 + r0) * K + swcolh;
  const __half* pb1 = Bm + (size_t)(bn * 256 + 1 * 64 + r0) * K + swcolh;
  const __half* pb2 = Bm + (size_t)(bn * 256 + 2 * 64 + r0) * K + swcolh;
  const __half* pb3 = Bm + (size_t)(bn * 256 + 3 * 64 + r0) * K + swcolh;

  auto stage = [&](int kt, int buf) {
    const int ko = kt * 64;
    char* ad = (char*)As[buf] + w * 1024;
    char* bd = (char*)Bs[buf] + w * 1024;
    gload_lds16(pa0 + ko, ad);
    gload_lds16(pa1 + ko, ad + 8192);
    gload_lds16(pa2 + ko, ad + 16384);
    gload_lds16(pa3 + ko, ad + 24576);
    gload_lds16(pb0 + ko, bd);
    gload_lds16(pb1 + ko, bd + 8192);
    gload_lds16(pb2 + ko, bd + 16384);
    gload_lds16(pb3 + ko, bd + 24576);
  };

  f32x4 acc[8][4];
  #pragma unroll
  for (int i = 0; i < 8; ++i)
    #pragma unroll
    for (int j = 0; j < 4; ++j) {
      acc[i][j][0] = 0.f; acc[i][j][1] = 0.f; acc[i][j][2] = 0.f; acc[i][j][3] = 0.f;
    }

  const int nk = K >> 6;   // BK=64
  stage(0, 0);

  int buf = 0;
  for (int kt = 0; kt < nk; ++kt) {
    __syncthreads();       // buf staged & drained (full K-step of compute since issue)
    if (kt + 1 < nk) stage(kt + 1, buf ^ 1);
    const char* as = (const char*)As[buf];
    const char* bs = (const char*)Bs[buf];
    #pragma unroll
    for (int kk = 0; kk < 2; ++kk) {
      const int cb = (kk * 64 + kseg * 16) ^ swzr;
      half8 af[8], bf[4];
      #pragma unroll
      for (int i = 0; i < 8; ++i)
        af[i] = *(const half8*)(as + (wr * 128 + i * 16 + l15) * 128 + cb);
      #pragma unroll
      for (int j = 0; j < 4; ++j)
        bf[j] = *(const half8*)(bs + (wc * 64 + j * 16 + l15) * 128 + cb);
      #pragma unroll
      for (int i = 0; i < 8; ++i)
        #pragma unroll
        for (int j = 0; j < 4; ++j)
          acc[i][j] = MFMA16(af[i], bf[j], acc[i][j]);
    }
    buf ^= 1;
  }

  const int crow0 = bm * 256 + wr * 128;
  const int ccol0 = bn * 256 + wc * 64;
  #pragma unroll
  for (int j = 0; j < 4; ++j) {
    const int c = ccol0 + j * 16 + l15;
    const float bv = bias[c];
    #pragma unroll
    for (int i = 0; i < 8; ++i) {
      #pragma unroll
      for (int r = 0; r < 4; ++r) {
        const int row = crow0 + i * 16 + kseg * 4 + r;
        Cout[(size_t)row * Ndim + c] = __float2half_rn(acc[i][j][r] + bv);
      }
    }
  }
}

// ---------------- flash attention, 32x32 swapped-operand structure ----------
// 8 waves x 32 q = 256 q rows per block; grid 512 blocks, XCD-swizzled.
// 4-buffer K/V (64 KB LDS, 2 blocks/CU), ONE barrier per 2 KV tiles; two
// independent QK->SM->PV chains per iteration (round-14, 130->119 us).
// CHUNK(sv, c): keys kb+16c..+15; source scores sv[8*(c&1) .. +7].
// key(j) = kb + 16c + 8*(j>>2) + (j&3) + 4*hi  (C-frag row map, m74/m101).
#define CHUNK(sv, c) do {                                                   \
    const int base2_ = qw - kb - 16 * (c);                                  \
    float ex_[8];                                                           \
    if (base2_ >= 47) {                                                     \
      _Pragma("unroll")                                                     \
      for (int j_ = 0; j_ < 8; ++j_)                                        \
        ex_[j_] = __builtin_amdgcn_exp2f(                                   \
            fmaf(sv[8 * ((c) & 1) + j_], kscale, mbs_hi));                  \
    } else if (base2_ <= -63) {                                             \
      _Pragma("unroll")                                                     \
      for (int j_ = 0; j_ < 8; ++j_)                                        \
        ex_[j_] = __builtin_amdgcn_exp2f(                                   \
            fmaf(sv[8 * ((c) & 1) + j_], kscale, mbs_lo));                  \
    } else {                                                                \
      _Pragma("unroll")                                                     \
      for (int j_ = 0; j_ < 8; ++j_) {                                      \
        int d_ = qs - (kb + 16 * (c) + 8 * (j_ >> 2) + (j_ & 3) + 4 * hi);  \
        d_ = min(max(d_, -32), 32);                                         \
        ex_[j_] = __builtin_amdgcn_exp2f(                                   \
            fmaf(sv[8 * ((c) & 1) + j_], kscale, mb[d_ + 32]));             \
      }                                                                     \
    }                                                                       \
    _Pragma("unroll")                                                       \
    for (int j_ = 0; j_ < 8; ++j_) lp4[j_ & 3] += ex_[j_];                  \
    uint32_t QA0_ = pkrtz(ex_[0], ex_[1]);                                  \
    uint32_t QA1_ = pkrtz(ex_[2], ex_[3]);                                  \
    uint32_t QB0_ = pkrtz(ex_[4], ex_[5]);                                  \
    uint32_t QB1_ = pkrtz(ex_[6], ex_[7]);                                  \
    auto r0_ = __builtin_amdgcn_permlane32_swap(QA0_, QB0_, false, false);  \
    auto r1_ = __builtin_amdgcn_permlane32_swap(QA1_, QB1_, false, false);  \
    u32x4 uv_;                                                              \
    uv_[0] = r0_[0]; uv_[1] = r1_[0]; uv_[2] = r0_[1]; uv_[3] = r1_[1];     \
    half8 ap_ = __builtin_bit_cast(half8, uv_);                             \
    const int cby_ = (32 * (c) + 16 * hi) ^ swzv;                           \
    half8 bv0_ = *(const half8*)(vtb + l31 * 128 + cby_);                   \
    half8 bv1_ = *(const half8*)(vtb + (32 + l31) * 128 + cby_);            \
    o0 = MFMA32(ap_, bv0_, o0);                                             \
    o1 = MFMA32(ap_, bv1_, o1);                                             \
  } while (0)

__global__ __launch_bounds__(512)
void attn_kernel(const __half* __restrict__ qkv, const float* __restrict__ mb,
                 __half* __restrict__ attn_out) {
  __shared__ __align__(16) __half Ks[4][64 * 64];
  __shared__ __align__(16) __half Vts[4][64 * 64];   // total LDS = 65536 B

  const int tid = threadIdx.x;
  const int lane = tid & 63;
  const int w = tid >> 6;            // 0..7
  const int l31 = lane & 31;
  const int hi = lane >> 5;
  // XCD-aware bijective swizzle: 512 blocks = 8 XCDs x 64 contiguous ids,
  // so the 8 q-blocks sharing one (b,h) KV panel land on ONE XCD's L2.
  const int flat = (blockIdx.y << 3) | blockIdx.x;
  const int nid = (flat & 7) * 64 + (flat >> 3);
  const int bh = nid >> 3;
  const int b = bh >> 4, h = bh & 15;
  const int qw = (nid & 7) * 256 + w * 32;        // wave's q base
  const int qs = qw + l31;                        // this lane's q (ST col)
  const float kscale = 0.125f * 1.44269504f;
  const int swzv = (l31 & 7) << 4;

  const float mbs_lo = mb[0];
  const float mbs_hi = mb[64];

  // Q B-frags: row j=q=l31, k(d) = 16s + 8hi + e
  const size_t qrow = (size_t)(b * 2048 + qs) * 3072;
  half8 bq[4];
  #pragma unroll
  for (int s = 0; s < 4; ++s)
    bq[s] = *(const half8*)&qkv[qrow + h * 64 + s * 16 + hi * 8];

  // K staging (pre-swizzled source, linear LDS dest): 1 x 16B per thread,
  // thread covers row tid>>3 (0..63), col bytes (tid&7)*16.
  const int krow0 = tid >> 3;
  const int kcolsw = ((tid & 7) * 16) ^ ((krow0 & 7) << 4);
  const __half* kp0 = qkv + (size_t)(b * 2048 + krow0) * 3072 + 1024 + h * 64 + (kcolsw >> 1);

  // V staging: thread covers key=lane (1 key) x 8 d (w*8 .. w*8+7).
  // LDS write: (lane*2)^(e<<4) covers all 64 even halfword slots of the row
  // -> 2 lanes/dword (minimal). Global: 16B/lane, L2-shared lines.
  const int vds = w * 8;
  const __half* vp = qkv + (size_t)(b * 2048 + lane) * 3072 + 2048 + h * 64 + vds;

  const size_t kvstep = (size_t)64 * 3072;

  f32x4 lp4 = {0.f, 0.f, 0.f, 0.f};
  f32x16 o0, o1;
  #pragma unroll
  for (int i = 0; i < 16; ++i) { o0[i] = 0.f; o1[i] = 0.f; }

  // ---- prologue: stage tiles 0,1; prefetch V for tiles 2,3 ----
  gload_lds16(kp0, (char*)Ks[0] + w * 1024);
  gload_lds16(kp0 + kvstep, (char*)Ks[1] + w * 1024);
  half8 va = *(const half8*)vp;
  half8 vb = *(const half8*)(vp + kvstep);
  #pragma unroll
  for (int e = 0; e < 8; ++e) {
    *(__half*)((char*)Vts[0] + (vds + e) * 128 + ((lane * 2) ^ (e << 4))) = (__half)va[e];
    *(__half*)((char*)Vts[1] + (vds + e) * 128 + ((lane * 2) ^ (e << 4))) = (__half)vb[e];
  }
  va = *(const half8*)(vp + 2 * kvstep);
  vb = *(const half8*)(vp + 3 * kvstep);

  // per-tile compute: QK^T (swapped) -> fused softmax/pack/PV
  auto compute_tile = [&](int kb, const char* ksb, const char* vtb) {
    f32x16 s0, s1;
    #pragma unroll
    for (int i = 0; i < 16; ++i) { s0[i] = 0.f; s1[i] = 0.f; }
    __builtin_amdgcn_s_setprio(1);
    #pragma unroll
    for (int s = 0; s < 4; ++s) {
      const int cby = (s * 32 + hi * 16) ^ swzv;
      half8 ak0 = *(const half8*)(ksb + l31 * 128 + cby);
      half8 ak1 = *(const half8*)(ksb + (32 + l31) * 128 + cby);
      s0 = MFMA32(ak0, bq[s], s0);
      s1 = MFMA32(ak1, bq[s], s1);
    }
    __builtin_amdgcn_s_setprio(0);
    __builtin_amdgcn_s_setprio(1);
    CHUNK(s0, 0);
    CHUNK(s0, 1);
    CHUNK(s1, 2);
    CHUNK(s1, 3);
    __builtin_amdgcn_s_setprio(0);
  };

  for (int kt = 0; kt < 32; kt += 2) {
    __syncthreads();   // tiles kt,kt+1 staged & ready; kt+2/kt+3 bufs free

    if (kt < 30) {
      const size_t adv2 = (size_t)(kt + 2) * kvstep;
      const size_t adv3 = (size_t)(kt + 3) * kvstep;
      gload_lds16(kp0 + adv2, (char*)Ks[(kt + 2) & 3] + w * 1024);
      gload_lds16(kp0 + adv3, (char*)Ks[(kt + 3) & 3] + w * 1024);
      char* v2 = (char*)Vts[(kt + 2) & 3];
      char* v3 = (char*)Vts[(kt + 3) & 3];
      #pragma unroll
      for (int e = 0; e < 8; ++e) {
        const int sw = (lane * 2) ^ (e << 4);
        *(__half*)(v2 + (vds + e) * 128 + sw) = (__half)va[e];
        *(__half*)(v3 + (vds + e) * 128 + sw) = (__half)vb[e];
      }
      if (kt < 28) {
        va = *(const half8*)(vp + (size_t)(kt + 4) * kvstep);
        vb = *(const half8*)(vp + (size_t)(kt + 5) * kvstep);
      }
    }

    compute_tile(kt * 64, (const char*)Ks[kt & 3], (const char*)Vts[kt & 3]);
    compute_tile((kt + 1) * 64, (const char*)Ks[(kt + 1) & 3],
                 (const char*)Vts[(kt + 1) & 3]);
  }

  // ---- final l reduction; lshare aliases Ks[1] (dead: tile 29 was its last
  // reader, and all waves passed the kt=30 barrier since) ----
  float lp = (lp4[0] + lp4[1]) + (lp4[2] + lp4[3]);
  lp += __shfl_xor(lp, 32, 64);
  float* lsh = ((float*)Ks[1]) + w * 32;
  if (hi == 0) lsh[l31] = lp;
  #pragma unroll
  for (int r = 0; r < 16; ++r) {
    const int ql = (r & 3) + 8 * (r >> 2) + 4 * hi;
    const float rl = 1.f / lsh[ql];
    const size_t row = (size_t)(b * 2048 + qw + ql) * 1024 + h * 64;
    attn_out[row + l31]      = __float2half(o0[r] * rl);
    attn_out[row + 32 + l31] = __float2half(o1[r] * rl);
  }
}

// ---------------- launch ----------------------------------------------------
extern "C" void kernel_launch(void* const* d_in, const int* in_sizes, int n_in,
                              void* d_out, int out_size, void* d_ws, size_t ws_size,
                              hipStream_t stream) {
  const float* x    = (const float*)d_in[0];  // [4,2048,1024]
  const float* in_w = (const float*)d_in[1];  // [3072,1024]
  const float* in_b = (const float*)d_in[2];  // [3072]
  const float* ow   = (const float*)d_in[3];  // [1024,1024]
  const float* ob   = (const float*)d_in[4];  // [1024]
  const float* rb   = (const float*)d_in[5];  // [65,16]

  char* ws = (char*)d_ws;
  __half* xh   = (__half*)(ws);                    // 16,777,216 B
  __half* wh   = (__half*)(ws + 16777216);         //  6,291,456 B
  __half* owh  = (__half*)(ws + 23068672);         //  2,097,152 B
  float*  mb   = (float*)(ws + 25165824);          //        512 B
  __half* qkvh = (__half*)(ws + 25166336);         // 50,331,648 B
  __half* atth = (__half*)(ws + 75497984);         // 16,777,216 B  (total ~92.3 MB)

  // fused conversions + bias mean (1 launch instead of 4)
  cvt_all<<<2048, 256, 0, stream>>>(x, in_w, ow, rb, xh, wh, owh, mb,
                                    (8192 * 1024) / 8, (3072 * 1024) / 8,
                                    (1024 * 1024) / 8);

  // qkv = x @ in_w^T + in_b : M=8192, N=3072, K=1024 — 256^2 tile (384 blocks)
  gemm256<<<dim3(12, 32), 512, 0, stream>>>(xh, wh, in_b, qkvh, 3072, 1024);
  // attention (256 q rows per block, 8 waves, 2 KV tiles per barrier)
  attn_kernel<<<dim3(8, 64), 512, 0, stream>>>(qkvh, mb, atth);
  // out = attn @ ow^T + ob : M=8192, N=1024, K=1024 — 128^2 tile (512 blocks)
  gemm_bt<false><<<dim3(8, 64), 256, 0, stream>>>(atth, owh, ob, (float*)d_out, 1024, 1024);
}

// Round 19
// 208.011 us; speedup vs baseline: 1.0389x; 1.0389x over previous
//
#include <hip/hip_runtime.h>
#include <hip/hip_fp16.h>
#include <stdint.h>
#include <stddef.h>

// B=4, S=2048, E=1024, H=16, D=64, M=32
// fp16 MFMA pipeline with fp32 accumulation everywhere.
// Round-15/17 configuration (session best, 208.2 us, reproduced twice).
// Round-18's 256^2 gemm1 regressed (+8 us): 128 KB LDS -> 1 block/CU, and
// 384 blocks on 256 CUs = 2 dispatch rounds (2nd half-idle) -> utilization
// loss > LDS-amortization gain. Reverted per pre-commit.

typedef _Float16 half8 __attribute__((ext_vector_type(8)));
typedef _Float16 half2v __attribute__((ext_vector_type(2)));
typedef float f32x4 __attribute__((ext_vector_type(4)));
typedef float f32x16 __attribute__((ext_vector_type(16)));
typedef uint32_t u32x4 __attribute__((ext_vector_type(4)));

#define MFMA16(a, b, c) __builtin_amdgcn_mfma_f32_16x16x32_f16(a, b, c, 0, 0, 0)
#define MFMA32(a, b, c) __builtin_amdgcn_mfma_f32_32x32x16_f16(a, b, c, 0, 0, 0)

__device__ static inline void gload_lds16(const void* g, void* l) {
  __builtin_amdgcn_global_load_lds(
      (const __attribute__((address_space(1))) void*)g,
      (__attribute__((address_space(3))) void*)l, 16, 0, 0);
}

// single-instruction packed f32->f16 (RTZ) convert: v_cvt_pkrtz_f16_f32
__device__ static inline uint32_t pkrtz(float a, float b) {
  return __builtin_bit_cast(uint32_t, __builtin_amdgcn_cvt_pkrtz(a, b));
}

// ---- fused f32->f16 conversion for x / in_w / out_w + rel_bias mean --------
__global__ void cvt_all(const float* __restrict__ x, const float* __restrict__ w,
                        const float* __restrict__ ow, const float* __restrict__ rb,
                        __half* __restrict__ xh, __half* __restrict__ wh,
                        __half* __restrict__ owh, float* __restrict__ mbg,
                        int nx, int nw, int no) {
  if (blockIdx.x == 0 && threadIdx.x < 65) {
    float s = 0.f;
    #pragma unroll
    for (int hh = 0; hh < 16; ++hh) s += rb[threadIdx.x * 16 + hh];
    mbg[threadIdx.x] = s * (1.44269504f / 16.f);  // mean * log2(e)
  }
  const int total = nx + nw + no;
  int i = blockIdx.x * blockDim.x + threadIdx.x;
  const int stride = gridDim.x * blockDim.x;
  for (; i < total; i += stride) {
    const float* src; __half* dst; int j;
    if (i < nx)            { src = x;  dst = xh;  j = i; }
    else if (i < nx + nw)  { src = w;  dst = wh;  j = i - nx; }
    else                   { src = ow; dst = owh; j = i - nx - nw; }
    const float4* p = (const float4*)src + (size_t)j * 2;
    float4 a = p[0], b = p[1];
    half8 hv;
    hv[0] = (_Float16)a.x; hv[1] = (_Float16)a.y; hv[2] = (_Float16)a.z; hv[3] = (_Float16)a.w;
    hv[4] = (_Float16)b.x; hv[5] = (_Float16)b.y; hv[6] = (_Float16)b.z; hv[7] = (_Float16)b.w;
    *(half8*)(dst + (size_t)j * 8) = hv;
  }
}

// ---------------- m97-style GEMM, 3-buffer pipelined staging ----------------
// One barrier per K-step; stage kt+2 right after the barrier; the vmcnt(0)
// drain at barrier kt waits on loads issued a full K-step earlier (~free).
// LDS 48 KB -> 3 blocks/CU. XCD-swizzled grid (nwg % 8 == 0).
template <bool OUT_HALF>
__global__ __launch_bounds__(256)
void gemm_bt(const __half* __restrict__ A, const __half* __restrict__ Bm,
             const float* __restrict__ bias, void* __restrict__ Cout,
             int Ndim, int K) {
  __shared__ __align__(16) __half As[3][128 * 32];
  __shared__ __align__(16) __half Bs[3][128 * 32];
  const int tid = threadIdx.x;
  const int lane = tid & 63;
  const int wave = tid >> 6;
  const int wr = wave >> 1, wc = wave & 1;
  const int flat = blockIdx.y * gridDim.x + blockIdx.x;
  const int cpx = (gridDim.x * gridDim.y) >> 3;
  const int nid = (flat & 7) * cpx + (flat >> 3);
  const int bn = nid % gridDim.x;
  const int bm = nid / gridDim.x;
  const int l15 = lane & 15;
  const int kseg = lane >> 4;

  const int off0 = tid * 16;
  const int mloc0 = off0 >> 6, kb0 = off0 & 63;
  const int off1 = 4096 + tid * 16;
  const int mloc1 = off1 >> 6, kb1 = off1 & 63;
  const __half* a0 = A + (size_t)(bm * 128 + mloc0) * K + (kb0 >> 1);
  const __half* a1 = A + (size_t)(bm * 128 + mloc1) * K + (kb1 >> 1);
  const __half* b0 = Bm + (size_t)(bn * 128 + mloc0) * K + (kb0 >> 1);
  const __half* b1 = Bm + (size_t)(bn * 128 + mloc1) * K + (kb1 >> 1);

  auto stage = [&](int kt, int buf) {
    char* ad = (char*)As[buf] + wave * 1024;
    char* bd = (char*)Bs[buf] + wave * 1024;
    gload_lds16(a0 + kt * 32, ad);
    gload_lds16(a1 + kt * 32, ad + 4096);
    gload_lds16(b0 + kt * 32, bd);
    gload_lds16(b1 + kt * 32, bd + 4096);
  };

  f32x4 acc[4][4];
  #pragma unroll
  for (int i = 0; i < 4; ++i)
    #pragma unroll
    for (int j = 0; j < 4; ++j) {
      acc[i][j][0] = 0.f; acc[i][j][1] = 0.f; acc[i][j][2] = 0.f; acc[i][j][3] = 0.f;
    }

  const int nk = K >> 5;
  stage(0, 0);
  stage(1, 1);

  int buf = 0;
  for (int kt = 0; kt < nk; ++kt) {
    __syncthreads();
    if (kt + 2 < nk) {
      int nb = buf + 2; if (nb >= 3) nb -= 3;
      stage(kt + 2, nb);
    }
    const __half* as = As[buf];
    const __half* bs = Bs[buf];
    half8 af[4], bf[4];
    #pragma unroll
    for (int i = 0; i < 4; ++i) {
      af[i] = *(const half8*)&as[(wr * 64 + i * 16 + l15) * 32 + kseg * 8];
      bf[i] = *(const half8*)&bs[(wc * 64 + i * 16 + l15) * 32 + kseg * 8];
    }
    #pragma unroll
    for (int i = 0; i < 4; ++i)
      #pragma unroll
      for (int j = 0; j < 4; ++j)
        acc[i][j] = MFMA16(af[i], bf[j], acc[i][j]);
    if (++buf == 3) buf = 0;
  }

  const int crow0 = bm * 128 + wr * 64;
  const int ccol0 = bn * 128 + wc * 64;
  #pragma unroll
  for (int j = 0; j < 4; ++j) {
    const int c = ccol0 + j * 16 + l15;
    const float bv = bias[c];
    #pragma unroll
    for (int i = 0; i < 4; ++i) {
      #pragma unroll
      for (int r = 0; r < 4; ++r) {
        const int row = crow0 + i * 16 + kseg * 4 + r;
        const float v = acc[i][j][r] + bv;
        if (OUT_HALF)
          ((__half*)Cout)[(size_t)row * Ndim + c] = __float2half_rn(v);
        else
          ((float*)Cout)[(size_t)row * Ndim + c] = v;
      }
    }
  }
}

// ---------------- flash attention, 32x32 swapped-operand structure ----------
// 8 waves x 32 q = 256 q rows per block; grid 512 blocks, XCD-swizzled.
// 4-buffer K/V (64 KB LDS, 2 blocks/CU), ONE barrier per 2 KV tiles; two
// independent QK->SM->PV chains per iteration (round-14, 130->119 us).
// CHUNK(sv, c): keys kb+16c..+15; source scores sv[8*(c&1) .. +7].
// key(j) = kb + 16c + 8*(j>>2) + (j&3) + 4*hi  (C-frag row map, m74/m101).
#define CHUNK(sv, c) do {                                                   \
    const int base2_ = qw - kb - 16 * (c);                                  \
    float ex_[8];                                                           \
    if (base2_ >= 47) {                                                     \
      _Pragma("unroll")                                                     \
      for (int j_ = 0; j_ < 8; ++j_)                                        \
        ex_[j_] = __builtin_amdgcn_exp2f(                                   \
            fmaf(sv[8 * ((c) & 1) + j_], kscale, mbs_hi));                  \
    } else if (base2_ <= -63) {                                             \
      _Pragma("unroll")                                                     \
      for (int j_ = 0; j_ < 8; ++j_)                                        \
        ex_[j_] = __builtin_amdgcn_exp2f(                                   \
            fmaf(sv[8 * ((c) & 1) + j_], kscale, mbs_lo));                  \
    } else {                                                                \
      _Pragma("unroll")                                                     \
      for (int j_ = 0; j_ < 8; ++j_) {                                      \
        int d_ = qs - (kb + 16 * (c) + 8 * (j_ >> 2) + (j_ & 3) + 4 * hi);  \
        d_ = min(max(d_, -32), 32);                                         \
        ex_[j_] = __builtin_amdgcn_exp2f(                                   \
            fmaf(sv[8 * ((c) & 1) + j_], kscale, mb[d_ + 32]));             \
      }                                                                     \
    }                                                                       \
    _Pragma("unroll")                                                       \
    for (int j_ = 0; j_ < 8; ++j_) lp4[j_ & 3] += ex_[j_];                  \
    uint32_t QA0_ = pkrtz(ex_[0], ex_[1]);                                  \
    uint32_t QA1_ = pkrtz(ex_[2], ex_[3]);                                  \
    uint32_t QB0_ = pkrtz(ex_[4], ex_[5]);                                  \
    uint32_t QB1_ = pkrtz(ex_[6], ex_[7]);                                  \
    auto r0_ = __builtin_amdgcn_permlane32_swap(QA0_, QB0_, false, false);  \
    auto r1_ = __builtin_amdgcn_permlane32_swap(QA1_, QB1_, false, false);  \
    u32x4 uv_;                                                              \
    uv_[0] = r0_[0]; uv_[1] = r1_[0]; uv_[2] = r0_[1]; uv_[3] = r1_[1];     \
    half8 ap_ = __builtin_bit_cast(half8, uv_);                             \
    const int cby_ = (32 * (c) + 16 * hi) ^ swzv;                           \
    half8 bv0_ = *(const half8*)(vtb + l31 * 128 + cby_);                   \
    half8 bv1_ = *(const half8*)(vtb + (32 + l31) * 128 + cby_);            \
    o0 = MFMA32(ap_, bv0_, o0);                                             \
    o1 = MFMA32(ap_, bv1_, o1);                                             \
  } while (0)

__global__ __launch_bounds__(512)
void attn_kernel(const __half* __restrict__ qkv, const float* __restrict__ mb,
                 __half* __restrict__ attn_out) {
  __shared__ __align__(16) __half Ks[4][64 * 64];
  __shared__ __align__(16) __half Vts[4][64 * 64];   // total LDS = 65536 B

  const int tid = threadIdx.x;
  const int lane = tid & 63;
  const int w = tid >> 6;            // 0..7
  const int l31 = lane & 31;
  const int hi = lane >> 5;
  // XCD-aware bijective swizzle: 512 blocks = 8 XCDs x 64 contiguous ids,
  // so the 8 q-blocks sharing one (b,h) KV panel land on ONE XCD's L2.
  const int flat = (blockIdx.y << 3) | blockIdx.x;
  const int nid = (flat & 7) * 64 + (flat >> 3);
  const int bh = nid >> 3;
  const int b = bh >> 4, h = bh & 15;
  const int qw = (nid & 7) * 256 + w * 32;        // wave's q base
  const int qs = qw + l31;                        // this lane's q (ST col)
  const float kscale = 0.125f * 1.44269504f;
  const int swzv = (l31 & 7) << 4;

  const float mbs_lo = mb[0];
  const float mbs_hi = mb[64];

  // Q B-frags: row j=q=l31, k(d) = 16s + 8hi + e
  const size_t qrow = (size_t)(b * 2048 + qs) * 3072;
  half8 bq[4];
  #pragma unroll
  for (int s = 0; s < 4; ++s)
    bq[s] = *(const half8*)&qkv[qrow + h * 64 + s * 16 + hi * 8];

  // K staging (pre-swizzled source, linear LDS dest): 1 x 16B per thread,
  // thread covers row tid>>3 (0..63), col bytes (tid&7)*16.
  const int krow0 = tid >> 3;
  const int kcolsw = ((tid & 7) * 16) ^ ((krow0 & 7) << 4);
  const __half* kp0 = qkv + (size_t)(b * 2048 + krow0) * 3072 + 1024 + h * 64 + (kcolsw >> 1);

  // V staging: thread covers key=lane (1 key) x 8 d (w*8 .. w*8+7).
  // LDS write: (lane*2)^(e<<4) covers all 64 even halfword slots of the row
  // -> 2 lanes/dword (minimal). Global: 16B/lane, L2-shared lines.
  const int vds = w * 8;
  const __half* vp = qkv + (size_t)(b * 2048 + lane) * 3072 + 2048 + h * 64 + vds;

  const size_t kvstep = (size_t)64 * 3072;

  f32x4 lp4 = {0.f, 0.f, 0.f, 0.f};
  f32x16 o0, o1;
  #pragma unroll
  for (int i = 0; i < 16; ++i) { o0[i] = 0.f; o1[i] = 0.f; }

  // ---- prologue: stage tiles 0,1; prefetch V for tiles 2,3 ----
  gload_lds16(kp0, (char*)Ks[0] + w * 1024);
  gload_lds16(kp0 + kvstep, (char*)Ks[1] + w * 1024);
  half8 va = *(const half8*)vp;
  half8 vb = *(const half8*)(vp + kvstep);
  #pragma unroll
  for (int e = 0; e < 8; ++e) {
    *(__half*)((char*)Vts[0] + (vds + e) * 128 + ((lane * 2) ^ (e << 4))) = (__half)va[e];
    *(__half*)((char*)Vts[1] + (vds + e) * 128 + ((lane * 2) ^ (e << 4))) = (__half)vb[e];
  }
  va = *(const half8*)(vp + 2 * kvstep);
  vb = *(const half8*)(vp + 3 * kvstep);

  // per-tile compute: QK^T (swapped) -> fused softmax/pack/PV
  auto compute_tile = [&](int kb, const char* ksb, const char* vtb) {
    f32x16 s0, s1;
    #pragma unroll
    for (int i = 0; i < 16; ++i) { s0[i] = 0.f; s1[i] = 0.f; }
    __builtin_amdgcn_s_setprio(1);
    #pragma unroll
    for (int s = 0; s < 4; ++s) {
      const int cby = (s * 32 + hi * 16) ^ swzv;
      half8 ak0 = *(const half8*)(ksb + l31 * 128 + cby);
      half8 ak1 = *(const half8*)(ksb + (32 + l31) * 128 + cby);
      s0 = MFMA32(ak0, bq[s], s0);
      s1 = MFMA32(ak1, bq[s], s1);
    }
    __builtin_amdgcn_s_setprio(0);
    __builtin_amdgcn_s_setprio(1);
    CHUNK(s0, 0);
    CHUNK(s0, 1);
    CHUNK(s1, 2);
    CHUNK(s1, 3);
    __builtin_amdgcn_s_setprio(0);
  };

  for (int kt = 0; kt < 32; kt += 2) {
    __syncthreads();   // tiles kt,kt+1 staged & ready; kt+2/kt+3 bufs free

    if (kt < 30) {
      const size_t adv2 = (size_t)(kt + 2) * kvstep;
      const size_t adv3 = (size_t)(kt + 3) * kvstep;
      gload_lds16(kp0 + adv2, (char*)Ks[(kt + 2) & 3] + w * 1024);
      gload_lds16(kp0 + adv3, (char*)Ks[(kt + 3) & 3] + w * 1024);
      char* v2 = (char*)Vts[(kt + 2) & 3];
      char* v3 = (char*)Vts[(kt + 3) & 3];
      #pragma unroll
      for (int e = 0; e < 8; ++e) {
        const int sw = (lane * 2) ^ (e << 4);
        *(__half*)(v2 + (vds + e) * 128 + sw) = (__half)va[e];
        *(__half*)(v3 + (vds + e) * 128 + sw) = (__half)vb[e];
      }
      if (kt < 28) {
        va = *(const half8*)(vp + (size_t)(kt + 4) * kvstep);
        vb = *(const half8*)(vp + (size_t)(kt + 5) * kvstep);
      }
    }

    compute_tile(kt * 64, (const char*)Ks[kt & 3], (const char*)Vts[kt & 3]);
    compute_tile((kt + 1) * 64, (const char*)Ks[(kt + 1) & 3],
                 (const char*)Vts[(kt + 1) & 3]);
  }

  // ---- final l reduction; lshare aliases Ks[1] (dead: tile 29 was its last
  // reader, and all waves passed the kt=30 barrier since) ----
  float lp = (lp4[0] + lp4[1]) + (lp4[2] + lp4[3]);
  lp += __shfl_xor(lp, 32, 64);
  float* lsh = ((float*)Ks[1]) + w * 32;
  if (hi == 0) lsh[l31] = lp;
  #pragma unroll
  for (int r = 0; r < 16; ++r) {
    const int ql = (r & 3) + 8 * (r >> 2) + 4 * hi;
    const float rl = 1.f / lsh[ql];
    const size_t row = (size_t)(b * 2048 + qw + ql) * 1024 + h * 64;
    attn_out[row + l31]      = __float2half(o0[r] * rl);
    attn_out[row + 32 + l31] = __float2half(o1[r] * rl);
  }
}

// ---------------- launch ----------------------------------------------------
extern "C" void kernel_launch(void* const* d_in, const int* in_sizes, int n_in,
                              void* d_out, int out_size, void* d_ws, size_t ws_size,
                              hipStream_t stream) {
  const float* x    = (const float*)d_in[0];  // [4,2048,1024]
  const float* in_w = (const float*)d_in[1];  // [3072,1024]
  const float* in_b = (const float*)d_in[2];  // [3072]
  const float* ow   = (const float*)d_in[3];  // [1024,1024]
  const float* ob   = (const float*)d_in[4];  // [1024]
  const float* rb   = (const float*)d_in[5];  // [65,16]

  char* ws = (char*)d_ws;
  __half* xh   = (__half*)(ws);                    // 16,777,216 B
  __half* wh   = (__half*)(ws + 16777216);         //  6,291,456 B
  __half* owh  = (__half*)(ws + 23068672);         //  2,097,152 B
  float*  mb   = (float*)(ws + 25165824);          //        512 B
  __half* qkvh = (__half*)(ws + 25166336);         // 50,331,648 B
  __half* atth = (__half*)(ws + 75497984);         // 16,777,216 B  (total ~92.3 MB)

  // fused conversions + bias mean (1 launch instead of 4)
  cvt_all<<<2048, 256, 0, stream>>>(x, in_w, ow, rb, xh, wh, owh, mb,
                                    (8192 * 1024) / 8, (3072 * 1024) / 8,
                                    (1024 * 1024) / 8);

  // qkv = x @ in_w^T + in_b : M=8192, N=3072, K=1024
  gemm_bt<true><<<dim3(24, 64), 256, 0, stream>>>(xh, wh, in_b, qkvh, 3072, 1024);
  // attention (256 q rows per block, 8 waves, 2 KV tiles per barrier)
  attn_kernel<<<dim3(8, 64), 512, 0, stream>>>(qkvh, mb, atth);
  // out = attn @ ow^T + ob : M=8192, N=1024, K=1024
  gemm_bt<false><<<dim3(8, 64), 256, 0, stream>>>(atth, owh, ob, (float*)d_out, 1024, 1024);
}